// Round 8
// baseline (253.146 us; speedup 1.0000x reference)
//
#include <hip/hip_runtime.h>
#include <hip/hip_fp16.h>

// GCN 2-layer forward: CSR-gather + fp16-MFMA GEMMs (fp32 accumulate).
// N=50000, E=800000, IN=128, HID=128, OUT=64.
// R8: gather128 split into 2 half-column dispatches (L2 footprint 12.8->6.4MB);
//     gemm128 fused into deg/posw dispatch; W converted fp32->fp16 inline in LDS staging.

typedef _Float16 f16;
typedef __attribute__((ext_vector_type(8))) _Float16 f16x8;
typedef __attribute__((ext_vector_type(4))) float f32x4;

// Per-block exclusive scan (block=1024); block sums to bsum; dinv on the side.
__global__ __launch_bounds__(1024) void scan1_kernel(const int* __restrict__ deg,
                                                     int* __restrict__ rowptr,
                                                     int* __restrict__ bsum,
                                                     float* __restrict__ dinv, int N) {
    __shared__ int wsum[16];
    const int tid = threadIdx.x, lane = tid & 63, wid = tid >> 6;
    const int idx = blockIdx.x * 1024 + tid;
    int v = (idx < N) ? deg[idx] : 0;
    if (idx < N) dinv[idx] = rsqrtf((float)v + 1.0f);
    int incl = v;
#pragma unroll
    for (int off = 1; off < 64; off <<= 1) {
        int t = __shfl_up(incl, off, 64);
        if (lane >= off) incl += t;
    }
    if (lane == 63) wsum[wid] = incl;
    __syncthreads();
    if (wid == 0) {
        int s = (lane < 16) ? wsum[lane] : 0;
#pragma unroll
        for (int off = 1; off < 16; off <<= 1) {
            int t = __shfl_up(s, off, 64);
            if (lane >= off) s += t;
        }
        if (lane < 16) wsum[lane] = s;
    }
    __syncthreads();
    int waveoff = (wid == 0) ? 0 : wsum[wid - 1];
    if (idx < N) rowptr[idx] = waveoff + incl - v;
    if (tid == 1023) bsum[blockIdx.x] = waveoff + incl;
}

// Merged scan2+scan3: each block adds its exclusive prefix of bsum (nb<=64);
// block 0 also writes rowptr[N] = total.
__global__ __launch_bounds__(1024) void scan23_kernel(int* __restrict__ rowptr,
                                                      const int* __restrict__ bsum,
                                                      int N, int nb) {
    __shared__ int pfx_s;
    const int tid = threadIdx.x;
    if (tid < 64) {
        int v = (tid < nb && tid < blockIdx.x) ? bsum[tid] : 0;
#pragma unroll
        for (int off = 32; off; off >>= 1) v += __shfl_xor(v, off, 64);
        if (tid == 0) pfx_s = v;
    }
    if (blockIdx.x == 0 && tid >= 64 && tid < 128) {
        int l = tid - 64;
        int v = (l < nb) ? bsum[l] : 0;
#pragma unroll
        for (int off = 32; off; off >>= 1) v += __shfl_xor(v, off, 64);
        if (l == 0) rowptr[N] = v;
    }
    __syncthreads();
    int idx = blockIdx.x * 1024 + tid;
    if (idx < N) rowptr[idx] += pfx_s;
}

// Atomic-free CSR fill: pos = rowptr[dst] + posw.
__global__ __launch_bounds__(256) void fill_kernel(const int* __restrict__ src,
                                                   const int* __restrict__ dst,
                                                   const int* __restrict__ posw,
                                                   const float* __restrict__ dinv,
                                                   const int* __restrict__ rowptr,
                                                   float2* __restrict__ pairs, int E) {
    int e = blockIdx.x * 256 + threadIdx.x;
    if (e >= E) return;
    int s = src[e], d = dst[e];
    float2 p;
    p.x = __int_as_float(s);
    p.y = dinv[s] * dinv[d];
    pairs[rowptr[d] + posw[e]] = p;
}

// GEMM body: H[N][KOUT](fp16) = X[N][128] @ W(fp32, row-major [128][KOUT]).
// W converted fp16 + transposed into LDS (Wl[c*136+k]) during staging.
// 256 thr = 4 waves x 16 rows per block.
template <int KOUT, bool F32IN>
__device__ __forceinline__ void gemm_body(int bid, const void* __restrict__ Xv,
                                          const float* __restrict__ W,
                                          f16* __restrict__ H, int N, f16* Wl) {
    constexpr int CT = KOUT / 16;
    const int tid = threadIdx.x;
    // stage+convert+transpose: W[k][c] f32 -> Wl[c*136+k] f16
    for (int i4 = tid; i4 < 128 * KOUT / 4; i4 += 256) {
        int flat = i4 * 4;
        int k = flat / KOUT, c = flat % KOUT;
        float4 w = *(const float4*)&W[flat];
        Wl[(c + 0) * 136 + k] = (f16)w.x;
        Wl[(c + 1) * 136 + k] = (f16)w.y;
        Wl[(c + 2) * 136 + k] = (f16)w.z;
        Wl[(c + 3) * 136 + k] = (f16)w.w;
    }
    __syncthreads();

    const int lane = tid & 63, wid = tid >> 6;
    const int c = lane & 15, kseg = lane >> 4;
    const int row0 = bid * 64 + wid * 16;
    int arow = row0 + c;
    if (arow >= N) arow = N - 1;

    f32x4 acc[CT];
#pragma unroll
    for (int t = 0; t < CT; ++t) acc[t] = (f32x4){0.f, 0.f, 0.f, 0.f};

#pragma unroll
    for (int kt = 0; kt < 4; ++kt) {
        const int k0 = kt * 32;
        f16x8 a;
        if (F32IN) {
            const float* xp = (const float*)Xv + (long)arow * 128 + k0 + kseg * 8;
            float4 x0 = *(const float4*)xp;
            float4 x1 = *(const float4*)(xp + 4);
            a[0] = (f16)x0.x; a[1] = (f16)x0.y; a[2] = (f16)x0.z; a[3] = (f16)x0.w;
            a[4] = (f16)x1.x; a[5] = (f16)x1.y; a[6] = (f16)x1.z; a[7] = (f16)x1.w;
        } else {
            a = *(const f16x8*)((const f16*)Xv + (long)arow * 128 + k0 + kseg * 8);
        }
#pragma unroll
        for (int ct = 0; ct < CT; ++ct) {
            f16x8 b = *(const f16x8*)&Wl[(ct * 16 + c) * 136 + k0 + kseg * 8];
            acc[ct] = __builtin_amdgcn_mfma_f32_16x16x32_f16(a, b, acc[ct], 0, 0, 0);
        }
    }

    const int rbase = row0 + kseg * 4;
#pragma unroll
    for (int ct = 0; ct < CT; ++ct)
#pragma unroll
        for (int r = 0; r < 4; ++r) {
            int row = rbase + r;
            if (row < N) H[(long)row * KOUT + ct * 16 + c] = (f16)acc[ct][r];
        }
}

// Standalone gemm (layer 2).
template <int KOUT, bool F32IN>
__global__ __launch_bounds__(256) void gemm_kernel(const void* __restrict__ Xv,
                                                   const float* __restrict__ W,
                                                   f16* __restrict__ H, int N) {
    __shared__ f16 Wl[KOUT * 136];
    gemm_body<KOUT, F32IN>(blockIdx.x, Xv, W, H, N, Wl);
}

// Fused: blocks [0,GB) run gemm128 x@W1->h1; blocks [GB,GB+DB) do deg histogram + posw.
__global__ __launch_bounds__(256) void deg_gemm_kernel(const int* __restrict__ dst,
                                                       int* __restrict__ deg,
                                                       int* __restrict__ posw, int E,
                                                       const float* __restrict__ x,
                                                       const float* __restrict__ W1,
                                                       f16* __restrict__ h1, int N, int GB) {
    __shared__ f16 Wl[128 * 136];
    if ((int)blockIdx.x < GB) {
        gemm_body<128, true>(blockIdx.x, x, W1, h1, N, Wl);
        return;
    }
    int e = (blockIdx.x - GB) * 256 + threadIdx.x;
    if (e < E) posw[e] = atomicAdd(&deg[dst[e]], 1);
}

// One wave per node; 1 half per lane per edge (128B line per edge).
// STRIDE: row stride of H in halves; COLOFF: column offset of this dispatch.
template <int STRIDE, int COLOFF, bool RELU, bool OUTF16>
__global__ __launch_bounds__(256) void gather_kernel(const __half* __restrict__ H,
                                                     const int* __restrict__ rowptr,
                                                     const float2* __restrict__ pairs,
                                                     const float* __restrict__ dinv,
                                                     const float* __restrict__ bias,
                                                     void* __restrict__ outv, int N) {
    const int wid = threadIdx.x >> 6;
    const int lane = threadIdx.x & 63;
    const int node = blockIdx.x * 4 + wid;
    if (node >= N) return;
    const int start = rowptr[node], end = rowptr[node + 1];
    const float4* pp4 = (const float4*)pairs;      // 2 edges per float4
    const __half* Hh = H + COLOFF + lane;

    float acc = 0.f;
    int e = start;
    if ((e & 1) && e < end) {  // align to even edge index for float4 pair loads
        float2 p0 = pairs[e];
        acc += __half2float(Hh[(long)__float_as_int(p0.x) * STRIDE]) * p0.y;
        ++e;
    }
    for (; e + 15 < end; e += 16) {
        float4 q[8];
#pragma unroll
        for (int j = 0; j < 8; ++j) q[j] = pp4[(e >> 1) + j];
        __half uu[16];
#pragma unroll
        for (int j = 0; j < 8; ++j) {
            uu[2 * j]     = Hh[(long)__float_as_int(q[j].x) * STRIDE];
            uu[2 * j + 1] = Hh[(long)__float_as_int(q[j].z) * STRIDE];
        }
#pragma unroll
        for (int j = 0; j < 8; ++j)
            acc += __half2float(uu[2 * j]) * q[j].y + __half2float(uu[2 * j + 1]) * q[j].w;
    }
    for (; e + 3 < end; e += 4) {
        float4 q0 = pp4[e >> 1], q1 = pp4[(e >> 1) + 1];
        float h0 = __half2float(Hh[(long)__float_as_int(q0.x) * STRIDE]);
        float h1 = __half2float(Hh[(long)__float_as_int(q0.z) * STRIDE]);
        float h2 = __half2float(Hh[(long)__float_as_int(q1.x) * STRIDE]);
        float h3 = __half2float(Hh[(long)__float_as_int(q1.z) * STRIDE]);
        acc += h0 * q0.y + h1 * q0.w + h2 * q1.y + h3 * q1.w;
    }
    for (; e < end; ++e) {
        float2 p0 = pairs[e];
        acc += __half2float(Hh[(long)__float_as_int(p0.x) * STRIDE]) * p0.y;
    }
    float di = dinv[node];
    float z = acc + __half2float(Hh[(long)node * STRIDE]) * (di * di) + bias[COLOFF + lane];
    if (RELU) z = fmaxf(z, 0.f);
    if (OUTF16) {
        ((__half*)outv)[(long)node * STRIDE + COLOFF + lane] = __float2half(z);
    } else {
        ((float*)outv)[(long)node * STRIDE + COLOFF + lane] = z;
    }
}

extern "C" void kernel_launch(void* const* d_in, const int* in_sizes, int n_in,
                              void* d_out, int out_size, void* d_ws, size_t ws_size,
                              hipStream_t stream) {
    const float* x  = (const float*)d_in[0];
    const int*   ei = (const int*)d_in[1];
    const float* W1 = (const float*)d_in[2];
    const float* b1 = (const float*)d_in[3];
    const float* W2 = (const float*)d_in[4];
    const float* b2 = (const float*)d_in[5];
    float* out = (float*)d_out;

    const int N = in_sizes[0] / 128;  // 50000
    const int E = in_sizes[1] / 2;    // 800000
    const int* src = ei;
    const int* dst = ei + E;
    const int NB = (N + 1023) / 1024;  // 49

    // workspace carving (float units; pairs at base => 16B-aligned for float4 loads)
    float* ws = (float*)d_ws;
    float2* pairs = (float2*)ws;                  // [E]
    long off = 2L * E;
    int* posw   = (int*)(ws + off); off += E;
    int* deg    = (int*)(ws + off); off += N;
    int* rowptr = (int*)(ws + off); off += N + 1;
    int* bsum   = (int*)(ws + off); off += 64;
    float* dinv = ws + off;        off += N;
    off = (off + 3) & ~3L;
    f16* h1 = (f16*)(ws + off); off += (long)N * 64;   // N*128 fp16
    f16* z1 = (f16*)(ws + off); off += (long)N * 64;   // N*128 fp16
    f16* h2 = (f16*)(ws + off); off += (long)N * 32;   // N*64 fp16

    const int GB = (N + 63) / 64;     // 782 gemm blocks
    const int DB = (E + 255) / 256;   // 3125 deg blocks

    // --- fused: gemm128 (x@W1 -> h1, W converted inline) + deg histogram/posw ---
    hipMemsetAsync(deg, 0, (size_t)N * sizeof(int), stream);
    deg_gemm_kernel<<<GB + DB, 256, 0, stream>>>(dst, deg, posw, E, x, W1, h1, N, GB);
    scan1_kernel<<<NB, 1024, 0, stream>>>(deg, rowptr, bsum, dinv, N);
    scan23_kernel<<<NB, 1024, 0, stream>>>(rowptr, bsum, N, NB);
    fill_kernel<<<(E + 255) / 256, 256, 0, stream>>>(src, dst, posw, dinv, rowptr, pairs, E);

    // --- layer 1 aggregate, split into two 64-column halves (smaller L2 footprint) ---
    gather_kernel<128, 0, true, true><<<(N + 3) / 4, 256, 0, stream>>>(
        (const __half*)h1, rowptr, pairs, dinv, b1, z1, N);
    gather_kernel<128, 64, true, true><<<(N + 3) / 4, 256, 0, stream>>>(
        (const __half*)h1, rowptr, pairs, dinv, b1, z1, N);

    // --- layer 2: h2 = f16(z1@W2); out = agg + self + b2 (fp32) ---
    gemm_kernel<64, false><<<(N + 63) / 64, 256, 0, stream>>>(z1, W2, h2, N);
    gather_kernel<64, 0, false, false><<<(N + 3) / 4, 256, 0, stream>>>(
        (const __half*)h2, rowptr, pairs, dinv, b2, out, N);
}

// Round 9
// 240.434 us; speedup vs baseline: 1.0529x; 1.0529x over previous
//
#include <hip/hip_runtime.h>
#include <hip/hip_fp16.h>

// GCN 2-layer forward: CSR-gather + fp16-MFMA GEMMs (fp32 accumulate).
// N=50000, E=800000, IN=128, HID=128, OUT=64.
// R9: scan chain replaced by atomic row-base assignment (CSR row order is arbitrary);
//     gather row loads via 32-bit byte offsets; W converted fp32->fp16 inline in LDS
//     staging; fill+gemm128 grid-fused (R7-proven); R8's regressions reverted.

typedef _Float16 f16;
typedef __attribute__((ext_vector_type(8))) _Float16 f16x8;
typedef __attribute__((ext_vector_type(4))) float f32x4;

// Histogram + per-edge within-row position.
__global__ __launch_bounds__(256) void deg_pos_kernel(const int* __restrict__ dst,
                                                      int* __restrict__ deg,
                                                      int* __restrict__ posw, int E) {
    int e = blockIdx.x * 256 + threadIdx.x;
    if (e < E) posw[e] = atomicAdd(&deg[dst[e]], 1);
}

// Row bases via atomic bump (order arbitrary); dinv on the side.
__global__ __launch_bounds__(256) void rowptr_kernel(const int* __restrict__ deg,
                                                     int* __restrict__ rowptr,
                                                     int* __restrict__ counter,
                                                     float* __restrict__ dinv, int N) {
    int i = blockIdx.x * 256 + threadIdx.x;
    if (i < N) {
        int d = deg[i];
        dinv[i] = rsqrtf((float)d + 1.0f);
        rowptr[i] = atomicAdd(counter, d);
    }
}

// GEMM body: H[N][KOUT](fp16) = X[N][128] @ W(fp32 row-major [128][KOUT]).
// W converted fp16 + transposed into LDS (Wl[c*136+k]) during staging.
template <int KOUT, bool F32IN>
__device__ __forceinline__ void gemm_body(int bid, const void* __restrict__ Xv,
                                          const float* __restrict__ W,
                                          f16* __restrict__ H, int N, f16* Wl) {
    constexpr int CT = KOUT / 16;
    const int tid = threadIdx.x;
    for (int i4 = tid; i4 < 128 * KOUT / 4; i4 += 256) {
        int flat = i4 * 4;
        int k = flat / KOUT, c = flat % KOUT;
        float4 w = *(const float4*)&W[flat];
        Wl[(c + 0) * 136 + k] = (f16)w.x;
        Wl[(c + 1) * 136 + k] = (f16)w.y;
        Wl[(c + 2) * 136 + k] = (f16)w.z;
        Wl[(c + 3) * 136 + k] = (f16)w.w;
    }
    __syncthreads();

    const int lane = tid & 63, wid = tid >> 6;
    const int c = lane & 15, kseg = lane >> 4;
    const int row0 = bid * 64 + wid * 16;
    int arow = row0 + c;
    if (arow >= N) arow = N - 1;

    f32x4 acc[CT];
#pragma unroll
    for (int t = 0; t < CT; ++t) acc[t] = (f32x4){0.f, 0.f, 0.f, 0.f};

#pragma unroll
    for (int kt = 0; kt < 4; ++kt) {
        const int k0 = kt * 32;
        f16x8 a;
        if (F32IN) {
            const float* xp = (const float*)Xv + (long)arow * 128 + k0 + kseg * 8;
            float4 x0 = *(const float4*)xp;
            float4 x1 = *(const float4*)(xp + 4);
            a[0] = (f16)x0.x; a[1] = (f16)x0.y; a[2] = (f16)x0.z; a[3] = (f16)x0.w;
            a[4] = (f16)x1.x; a[5] = (f16)x1.y; a[6] = (f16)x1.z; a[7] = (f16)x1.w;
        } else {
            a = *(const f16x8*)((const f16*)Xv + (long)arow * 128 + k0 + kseg * 8);
        }
#pragma unroll
        for (int ct = 0; ct < CT; ++ct) {
            f16x8 b = *(const f16x8*)&Wl[(ct * 16 + c) * 136 + k0 + kseg * 8];
            acc[ct] = __builtin_amdgcn_mfma_f32_16x16x32_f16(a, b, acc[ct], 0, 0, 0);
        }
    }

    const int rbase = row0 + kseg * 4;
#pragma unroll
    for (int ct = 0; ct < CT; ++ct)
#pragma unroll
        for (int r = 0; r < 4; ++r) {
            int row = rbase + r;
            if (row < N) H[(long)row * KOUT + ct * 16 + c] = (f16)acc[ct][r];
        }
}

// Standalone gemm (layer 2).
template <int KOUT, bool F32IN>
__global__ __launch_bounds__(256) void gemm_kernel(const void* __restrict__ Xv,
                                                   const float* __restrict__ W,
                                                   f16* __restrict__ H, int N) {
    __shared__ f16 Wl[KOUT * 136];
    gemm_body<KOUT, F32IN>(blockIdx.x, Xv, W, H, N, Wl);
}

// Fused: blocks [0,GB) run gemm128 x@W1->h1; blocks [GB,GB+FB) do CSR fill.
__global__ __launch_bounds__(256) void fill_gemm_kernel(const int* __restrict__ src,
                                                        const int* __restrict__ dst,
                                                        const int* __restrict__ posw,
                                                        const float* __restrict__ dinv,
                                                        const int* __restrict__ rowptr,
                                                        float2* __restrict__ pairs, int E,
                                                        const float* __restrict__ x,
                                                        const float* __restrict__ W1,
                                                        f16* __restrict__ h1, int N, int GB) {
    __shared__ f16 Wl[128 * 136];
    if ((int)blockIdx.x < GB) {
        gemm_body<128, true>(blockIdx.x, x, W1, h1, N, Wl);
        return;
    }
    int e = (blockIdx.x - GB) * 256 + threadIdx.x;
    if (e >= E) return;
    int s = src[e], d = dst[e];
    float2 p;
    p.x = __int_as_float(s);
    p.y = dinv[s] * dinv[d];
    pairs[rowptr[d] + posw[e]] = p;
}

// One wave per node; fp16 payloads, fp32 accumulate. Row loads via
// base + (src << SHIFT) byte offsets (fits 24 bits -> 32-bit voffset form).
// F=128: half2/lane (256B/edge). F=64: half/lane (128B/edge).
template <int F, bool RELU, bool OUTF16>
__global__ __launch_bounds__(256) void gather_kernel(const void* __restrict__ Hv,
                                                     const int* __restrict__ rowptr,
                                                     const int* __restrict__ deg,
                                                     const float2* __restrict__ pairs,
                                                     const float* __restrict__ dinv,
                                                     const float* __restrict__ bias,
                                                     void* __restrict__ outv, int N) {
    const int wid = threadIdx.x >> 6;
    const int lane = threadIdx.x & 63;
    const int node = blockIdx.x * 4 + wid;
    if (node >= N) return;
    const int start = rowptr[node];
    const int end = start + deg[node];
    const float4* pp4 = (const float4*)pairs;  // 2 edges per float4
    constexpr int SHIFT = (F == 128) ? 8 : 7;  // row bytes: 256 / 128
    const char* Hb = (const char*)Hv + lane * (F == 128 ? 4 : 2);

    float ax = 0.f, ay = 0.f;
    int e = start;
    if ((e & 1) && e < end) {  // align to even edge index for float4 pair loads
        float2 p0 = pairs[e];
        uint o = (uint)__float_as_int(p0.x) << SHIFT;
        if (F == 128) {
            float2 f0 = __half22float2(*(const __half2*)(Hb + o));
            ax += f0.x * p0.y; ay += f0.y * p0.y;
        } else {
            ax += __half2float(*(const __half*)(Hb + o)) * p0.y;
        }
        ++e;
    }
    for (; e + 15 < end; e += 16) {
        float4 q[8];
#pragma unroll
        for (int j = 0; j < 8; ++j) q[j] = pp4[(e >> 1) + j];
        uint off[16];
#pragma unroll
        for (int j = 0; j < 8; ++j) {
            off[2 * j]     = (uint)__float_as_int(q[j].x) << SHIFT;
            off[2 * j + 1] = (uint)__float_as_int(q[j].z) << SHIFT;
        }
        if (F == 128) {
            __half2 uu[16];
#pragma unroll
            for (int j = 0; j < 16; ++j) uu[j] = *(const __half2*)(Hb + off[j]);
#pragma unroll
            for (int j = 0; j < 8; ++j) {
                float2 f0 = __half22float2(uu[2 * j]);
                float2 f1 = __half22float2(uu[2 * j + 1]);
                ax += f0.x * q[j].y + f1.x * q[j].w;
                ay += f0.y * q[j].y + f1.y * q[j].w;
            }
        } else {
            __half uu[16];
#pragma unroll
            for (int j = 0; j < 16; ++j) uu[j] = *(const __half*)(Hb + off[j]);
#pragma unroll
            for (int j = 0; j < 8; ++j)
                ax += __half2float(uu[2 * j]) * q[j].y + __half2float(uu[2 * j + 1]) * q[j].w;
        }
    }
    for (; e + 3 < end; e += 4) {
        float4 q0 = pp4[e >> 1], q1 = pp4[(e >> 1) + 1];
        uint o0 = (uint)__float_as_int(q0.x) << SHIFT;
        uint o1 = (uint)__float_as_int(q0.z) << SHIFT;
        uint o2 = (uint)__float_as_int(q1.x) << SHIFT;
        uint o3 = (uint)__float_as_int(q1.z) << SHIFT;
        if (F == 128) {
            __half2 u0 = *(const __half2*)(Hb + o0);
            __half2 u1 = *(const __half2*)(Hb + o1);
            __half2 u2 = *(const __half2*)(Hb + o2);
            __half2 u3 = *(const __half2*)(Hb + o3);
            float2 f0 = __half22float2(u0), f1 = __half22float2(u1);
            float2 f2 = __half22float2(u2), f3 = __half22float2(u3);
            ax += f0.x * q0.y + f1.x * q0.w + f2.x * q1.y + f3.x * q1.w;
            ay += f0.y * q0.y + f1.y * q0.w + f2.y * q1.y + f3.y * q1.w;
        } else {
            float h0 = __half2float(*(const __half*)(Hb + o0));
            float h1 = __half2float(*(const __half*)(Hb + o1));
            float h2 = __half2float(*(const __half*)(Hb + o2));
            float h3 = __half2float(*(const __half*)(Hb + o3));
            ax += h0 * q0.y + h1 * q0.w + h2 * q1.y + h3 * q1.w;
        }
    }
    for (; e < end; ++e) {
        float2 p0 = pairs[e];
        uint o = (uint)__float_as_int(p0.x) << SHIFT;
        if (F == 128) {
            float2 f0 = __half22float2(*(const __half2*)(Hb + o));
            ax += f0.x * p0.y; ay += f0.y * p0.y;
        } else {
            ax += __half2float(*(const __half*)(Hb + o)) * p0.y;
        }
    }

    float di = dinv[node];
    float d2 = di * di;
    if (F == 128) {
        float2 fs = __half22float2(*(const __half2*)(Hb + ((uint)node << SHIFT)));
        float2 bz = ((const float2*)bias)[lane];
        float zx = ax + fs.x * d2 + bz.x;
        float zy = ay + fs.y * d2 + bz.y;
        if (RELU) { zx = fmaxf(zx, 0.f); zy = fmaxf(zy, 0.f); }
        if (OUTF16) {
            ((__half2*)outv)[(long)node * 64 + lane] = __float22half2_rn(make_float2(zx, zy));
        } else {
            float2 o = {zx, zy};
            ((float2*)outv)[(long)node * 64 + lane] = o;
        }
    } else {
        float z = ax + __half2float(*(const __half*)(Hb + ((uint)node << SHIFT))) * d2 + bias[lane];
        if (RELU) z = fmaxf(z, 0.f);
        if (OUTF16) ((__half*)outv)[(long)node * 64 + lane] = __float2half(z);
        else        ((float*)outv)[(long)node * 64 + lane] = z;
    }
}

extern "C" void kernel_launch(void* const* d_in, const int* in_sizes, int n_in,
                              void* d_out, int out_size, void* d_ws, size_t ws_size,
                              hipStream_t stream) {
    const float* x  = (const float*)d_in[0];
    const int*   ei = (const int*)d_in[1];
    const float* W1 = (const float*)d_in[2];
    const float* b1 = (const float*)d_in[3];
    const float* W2 = (const float*)d_in[4];
    const float* b2 = (const float*)d_in[5];
    float* out = (float*)d_out;

    const int N = in_sizes[0] / 128;  // 50000
    const int E = in_sizes[1] / 2;    // 800000
    const int* src = ei;
    const int* dst = ei + E;

    // workspace carving (float units; pairs at base => 16B-aligned for float4 loads)
    float* ws = (float*)d_ws;
    float2* pairs = (float2*)ws;                    // [E]
    long off = 2L * E;
    int* posw    = (int*)(ws + off); off += E;
    int* deg     = (int*)(ws + off); off += N;      // deg[N] then counter adjacent
    int* counter = (int*)(ws + off); off += 1;
    int* rowptr  = (int*)(ws + off); off += N;
    float* dinv  = ws + off;        off += N;
    off = (off + 3) & ~3L;
    f16* h1 = (f16*)(ws + off); off += (long)N * 64;   // N*128 fp16
    f16* z1 = (f16*)(ws + off); off += (long)N * 64;   // N*128 fp16
    f16* h2 = (f16*)(ws + off); off += (long)N * 32;   // N*64 fp16

    const int GB = (N + 63) / 64;     // 782 gemm blocks
    const int FB = (E + 255) / 256;   // 3125 fill blocks

    // --- CSR build (no scan: row bases via atomic bump) ---
    hipMemsetAsync(deg, 0, (size_t)(N + 1) * sizeof(int), stream);  // deg + counter
    deg_pos_kernel<<<FB, 256, 0, stream>>>(dst, deg, posw, E);
    rowptr_kernel<<<(N + 255) / 256, 256, 0, stream>>>(deg, rowptr, counter, dinv, N);
    fill_gemm_kernel<<<GB + FB, 256, 0, stream>>>(src, dst, posw, dinv, rowptr, pairs, E,
                                                  x, W1, h1, N, GB);

    // --- layer 1 aggregate: z1 = f16(relu(agg + self + b1)) ---
    gather_kernel<128, true, true><<<(N + 3) / 4, 256, 0, stream>>>(
        h1, rowptr, deg, pairs, dinv, b1, z1, N);

    // --- layer 2: h2 = f16(z1@W2); out = agg + self + b2 (fp32) ---
    gemm_kernel<64, false><<<(N + 63) / 64, 256, 0, stream>>>(z1, W2, h2, N);
    gather_kernel<64, false, false><<<(N + 3) / 4, 256, 0, stream>>>(
        h2, rowptr, deg, pairs, dinv, b2, out, N);
}